// Round 14
// baseline (211.231 us; speedup 1.0000x reference)
//
#include <hip/hip_runtime.h>

typedef unsigned short u16;
typedef _Float16 f16x8 __attribute__((ext_vector_type(8)));
typedef float f32x4 __attribute__((ext_vector_type(4)));
typedef unsigned short u16x4 __attribute__((ext_vector_type(4)));

#define HID 1024
#define SEQ 2048
#define NH 16
#define DH 64

// ---------- helpers ----------
__device__ __forceinline__ u16 f2h(float f) {
  return __builtin_bit_cast(u16, (_Float16)f);
}
__device__ __forceinline__ f32x4 mfma_h(f16x8 a, f16x8 b, f32x4 c) {
  return __builtin_amdgcn_mfma_f32_16x16x32_f16(a, b, c, 0, 0, 0);
}
// raw v_exp_f32 (2^x); libm exp2f is the branchy OCML path (r8 regression).
__device__ __forceinline__ float fexp2(float x) {
#if __has_builtin(__builtin_amdgcn_exp2f)
  return __builtin_amdgcn_exp2f(x);
#else
  return __expf(0.69314718f * x);
#endif
}
// async global->LDS, 16B per lane; LDS dest is wave-uniform base + lane*16
__device__ __forceinline__ void g2l16(const u16* g, u16* l) {
  __builtin_amdgcn_global_load_lds(
      (const __attribute__((address_space(1))) unsigned int*)g,
      (__attribute__((address_space(3))) unsigned int*)l, 16, 0, 0);
}

// ---------- fused prep: x->fp16, w_qkv->fp16, w_o->fp16 ----------
#define NX4 ((4096 * 1024) / 4)
#define NQ4 ((3072 * 1024) / 4)
#define NO4 ((1024 * 1024) / 4)
__global__ __launch_bounds__(256) void prep_kernel(
    const float* __restrict__ x, const float* __restrict__ wq,
    const float* __restrict__ wo,
    u16* __restrict__ x16, u16* __restrict__ wq16, u16* __restrict__ wo16) {
  int i = blockIdx.x * 256 + threadIdx.x;
  const float4 v = (i < NX4) ? ((const float4*)x)[i]
                 : (i < NX4 + NQ4) ? ((const float4*)wq)[i - NX4]
                 : ((const float4*)wo)[i - NX4 - NQ4];
  u16* dst = (i < NX4) ? &x16[(size_t)i * 4]
           : (i < NX4 + NQ4) ? &wq16[(size_t)(i - NX4) * 4]
           : &wo16[(size_t)(i - NX4 - NQ4) * 4];
  u16x4 o;
  o[0] = f2h(v.x); o[1] = f2h(v.y); o[2] = f2h(v.z); o[3] = f2h(v.w);
  *(u16x4*)dst = o;
}

// ---------- QKV GEMM, fp16 single-term, BK=32 (r7-proven m97 layout) ----------
// C = (1/32) * A[4096x1024] * B[3072x1024]^T; epilogue scatters
// q (prescaled by d^-0.5 * log2e), k [b,h,s,d], vT [b,h,d,s'] where s' is the
// per-64-tile kv interleave s' = 4*(kv&15) + (kv>>4) -- matches the packed-P
// k-order in attn (mfma sums over k symmetrically; A/B just need a COMMON order).
__global__ __launch_bounds__(256, 3) void gemm_qkv(
    const u16* __restrict__ a16, const u16* __restrict__ b16,
    u16* __restrict__ qf, u16* __restrict__ kf, u16* __restrict__ vtf) {
  __shared__ __align__(16) u16 la[128 * 32], lb[128 * 32];
  const int t = threadIdx.x;
  const int lane = t & 63, w = t >> 6;
  const int wr = w >> 1, wc = w & 1;
  const int lr = lane & 15, lg = lane >> 4;
  const int br = blockIdx.x, bc = blockIdx.y;
  const f32x4 fzero = {0.f, 0.f, 0.f, 0.f};
  f32x4 acc[4][4];
#pragma unroll
  for (int i = 0; i < 4; ++i)
#pragma unroll
    for (int j = 0; j < 4; ++j) acc[i][j] = fzero;
  const int srow = t >> 2, scol = (t & 3) << 3;
  const u16* ga = a16 + (size_t)(br * 128 + srow) * HID + scol;
  const u16* gb = b16 + (size_t)(bc * 128 + srow) * HID + scol;
  const int lo16 = t * 8;
  for (int kk = 0; kk < HID; kk += 32) {
    g2l16(ga + kk, &la[lo16]);
    g2l16(ga + kk + (size_t)64 * HID, &la[lo16 + 2048]);
    g2l16(gb + kk, &lb[lo16]);
    g2l16(gb + kk + (size_t)64 * HID, &lb[lo16 + 2048]);
    __syncthreads();
    f16x8 ah[4], bh[4];
#pragma unroll
    for (int i = 0; i < 4; ++i)
      ah[i] = *(const f16x8*)&la[(wr * 64 + i * 16 + lr) * 32 + lg * 8];
#pragma unroll
    for (int j = 0; j < 4; ++j)
      bh[j] = *(const f16x8*)&lb[(wc * 64 + j * 16 + lr) * 32 + lg * 8];
#pragma unroll
    for (int i = 0; i < 4; ++i)
#pragma unroll
      for (int j = 0; j < 4; ++j) acc[i][j] = mfma_h(ah[i], bh[j], acc[i][j]);
    __syncthreads();
  }
  const int m0 = br * 128 + wr * 64, n0 = bc * 128 + wc * 64;
#pragma unroll
  for (int i = 0; i < 4; ++i)
#pragma unroll
    for (int j = 0; j < 4; ++j)
#pragma unroll
      for (int r = 0; r < 4; ++r) {
        int row = m0 + i * 16 + lg * 4 + r;       // C/D: row=(lane>>4)*4+reg
        int col = n0 + j * 16 + lr;               //      col=lane&15
        float val = acc[i][j][r] * 0.03125f;      // * HID^-0.5
        int b = row >> 11, s = row & 2047;
        int z = col >> 10, hh = (col >> 6) & 15, d = col & 63;
        int bhid = b * NH + hh;
        if (z == 0) {
          // * DH^-0.5 * log2(e): softmax uses raw v_exp_f32 (2^x)
          qf[((size_t)bhid * SEQ + s) * DH + d] = f2h(val * 0.18033688f);
        } else if (z == 1) {
          kf[((size_t)bhid * SEQ + s) * DH + d] = f2h(val);
        } else {
          // kv-interleaved within each 64-tile: col' = 4*(kv&15) + (kv>>4)
          int s2 = (s & ~63) | ((s & 15) << 2) | ((s >> 4) & 3);
          vtf[((size_t)bhid * DH + d) * SEQ + s2] = f2h(val);
        }
      }
}

// ---------- out-proj: single-term fp16, BK=32, 128x64 tile ----------
__global__ __launch_bounds__(256, 2) void gemm_proj(
    const u16* __restrict__ a16, const u16* __restrict__ b16,
    float* __restrict__ out) {
  __shared__ __align__(16) u16 la[128 * 32];
  __shared__ __align__(16) u16 lb[64 * 32];
  const int t = threadIdx.x;
  const int lane = t & 63, w = t >> 6;
  const int wr = w >> 1, wc = w & 1;
  const int lr = lane & 15, lg = lane >> 4;
  const int br = blockIdx.x, bc = blockIdx.y;
  const f32x4 fzero = {0.f, 0.f, 0.f, 0.f};
  f32x4 acc[4][2];
#pragma unroll
  for (int i = 0; i < 4; ++i)
#pragma unroll
    for (int j = 0; j < 2; ++j) acc[i][j] = fzero;
  const int srow = t >> 2, scol = (t & 3) << 3;
  const u16* ga = a16 + (size_t)(br * 128 + srow) * HID + scol;
  const u16* gb = b16 + (size_t)(bc * 64 + srow) * HID + scol;
  const int lo16 = t * 8;
  for (int kk = 0; kk < HID; kk += 32) {
    g2l16(ga + kk, &la[lo16]);
    g2l16(ga + kk + (size_t)64 * HID, &la[lo16 + 2048]);
    g2l16(gb + kk, &lb[lo16]);
    __syncthreads();
    f16x8 ah[4], bh[2];
#pragma unroll
    for (int i = 0; i < 4; ++i)
      ah[i] = *(const f16x8*)&la[(wr * 64 + i * 16 + lr) * 32 + lg * 8];
#pragma unroll
    for (int j = 0; j < 2; ++j)
      bh[j] = *(const f16x8*)&lb[(wc * 32 + j * 16 + lr) * 32 + lg * 8];
#pragma unroll
    for (int i = 0; i < 4; ++i)
#pragma unroll
      for (int j = 0; j < 2; ++j)
        acc[i][j] = mfma_h(ah[i], bh[j], acc[i][j]);
    __syncthreads();
  }
  const int m0 = br * 128 + wr * 64, n0 = bc * 64 + wc * 32;
#pragma unroll
  for (int i = 0; i < 4; ++i)
#pragma unroll
    for (int j = 0; j < 2; ++j)
#pragma unroll
      for (int r = 0; r < 4; ++r) {
        int row = m0 + i * 16 + lg * 4 + r;
        int col = n0 + j * 16 + lr;
        out[(size_t)row * HID + col] = acc[i][j][r] * 0.03125f;
      }
}

// ---------- flash attention: r13 skeleton, K from global (L1/L2) ----------
// r14: K LDS tile + staging deleted; K fragments load straight to registers
// via coalesced global_load_dwordx4 (lanes form dense 64B lines). K(j+1)
// prefetched into the alternate register set after the P barrier (hidden
// under PV). Rationale: attn has no saturated pipe; LDS was the busiest
// (~57%) and 8/20 b128 reads were K. vmem pipe idle; per-block 8KB K-tile is
// L1-resident so the 4-wave redundancy is L1-served. V + P handoff (packed
// b64, kv-interleave) and both barriers unchanged. LDS 48KB -> 32KB.
__global__ __launch_bounds__(256, 2) void attn_kernel(
    const u16* __restrict__ qf, const u16* __restrict__ kf,
    const u16* __restrict__ vtf, u16* __restrict__ o16) {
  __shared__ __align__(16) u16 lv[2][64 * 64];   // V^T tile [d][kv'], fp16
  __shared__ __align__(16) u16 lp[128 * 64];     // P [q][kv'], fp16
  const int t = threadIdx.x;
  const int lane = t & 63, w = t >> 6;
  const int lr = lane & 15, lg = lane >> 4;
  const int bh = blockIdx.x, qt = blockIdx.y;
  const size_t base_qk = (size_t)bh * SEQ * DH;
  const size_t base_vt = (size_t)bh * DH * SEQ;

  // Q fragments pinned in registers (prescaled at creation)
  f16x8 qfr[2][2];
#pragma unroll
  for (int rt = 0; rt < 2; ++rt)
#pragma unroll
    for (int ks = 0; ks < 2; ++ks)
      qfr[rt][ks] = *(const f16x8*)&qf[base_qk +
          (size_t)(qt * 128 + w * 32 + rt * 16 + lr) * DH + ks * 32 + lg * 8];

  const f32x4 fzero = {0.f, 0.f, 0.f, 0.f};
  f32x4 acc_o[2][4];
  float l_i[2][4];
#pragma unroll
  for (int rt = 0; rt < 2; ++rt)
#pragma unroll
    for (int r = 0; r < 4; ++r) l_i[rt][r] = 0.f;
#pragma unroll
  for (int rt = 0; rt < 2; ++rt)
#pragma unroll
    for (int ct = 0; ct < 4; ++ct) acc_o[rt][ct] = fzero;

  // per-lane K base: row = j*64 + ct*16 + lr, col = ks*32 + lg*8
  const u16* kb = kf + base_qk + (size_t)lr * DH + lg * 8;
  f16x8 k0[8], k1[8];   // two K fragment sets (cur / prefetch)

#define LOADK(J, KR)                                                      \
  _Pragma("unroll") for (int ks = 0; ks < 2; ++ks)                        \
  _Pragma("unroll") for (int ct = 0; ct < 4; ++ct)                        \
    KR[ks * 4 + ct] =                                                     \
        *(const f16x8*)&kb[(size_t)((J) * 64 + ct * 16) * DH + ks * 32];

  // V staging: thread t fills phys chunk t (16B); source col XOR-permuted
  const int srow = t >> 3;                 // 0..31
  const int scol = ((t & 7) ^ (srow & 7)) << 3;
  const int lo16 = t * 8;
  const u16* gv0 = vtf + base_vt + (size_t)srow * SEQ + scol;

#define STAGE(buf, j)                                             \
  {                                                               \
    const u16* gv = gv0 + (j) * 64;                               \
    g2l16(gv, &lv[buf][lo16]);                                    \
    g2l16(gv + (size_t)32 * SEQ, &lv[buf][lo16 + 2048]);          \
  }

#define ATTN_ITER(J, KC, KN)                                              \
  {                                                                       \
    const int cur = (J) & 1;                                              \
    __syncthreads();   /* V(J) visible; lp free; KC arrived */            \
    f32x4 sa[2][4];                                                       \
    _Pragma("unroll") for (int rt = 0; rt < 2; ++rt)                      \
    _Pragma("unroll") for (int ct = 0; ct < 4; ++ct) sa[rt][ct] = fzero;  \
    _Pragma("unroll") for (int ks = 0; ks < 2; ++ks)                      \
    _Pragma("unroll") for (int ct = 0; ct < 4; ++ct) {                    \
      _Pragma("unroll") for (int rt = 0; rt < 2; ++rt)                    \
        sa[rt][ct] = mfma_h(qfr[rt][ks], KC[ks * 4 + ct], sa[rt][ct]);    \
    }                                                                     \
    _Pragma("unroll") for (int rt = 0; rt < 2; ++rt)                      \
    _Pragma("unroll") for (int r = 0; r < 4; ++r) {                       \
      float p0 = fexp2(sa[rt][0][r]);                                     \
      float p1 = fexp2(sa[rt][1][r]);                                     \
      float p2 = fexp2(sa[rt][2][r]);                                     \
      float p3 = fexp2(sa[rt][3][r]);                                     \
      l_i[rt][r] += (p0 + p1) + (p2 + p3);                                \
      int prow = w * 32 + rt * 16 + lg * 4 + r;                           \
      u16x4 pk;                                                           \
      pk[0] = f2h(p0); pk[1] = f2h(p1); pk[2] = f2h(p2); pk[3] = f2h(p3); \
      int phys = prow * 64 +                                              \
                 ((((lr >> 1) ^ (prow & 7)) << 3) | ((lr & 1) << 2));     \
      *(u16x4*)&lp[phys] = pk;                                            \
    }                                                                     \
    __syncthreads();   /* lp visible */                                   \
    if ((J) + 1 < SEQ / 64) {                                             \
      LOADK((J) + 1, KN)          /* prefetch K, hidden under PV */       \
      STAGE(((J) + 1) & 1, (J) + 1)                                       \
    }                                                                     \
    _Pragma("unroll") for (int ks = 0; ks < 2; ++ks) {                    \
      f16x8 pfr[2];                                                       \
      _Pragma("unroll") for (int rt = 0; rt < 2; ++rt) {                  \
        int prow = w * 32 + rt * 16 + lr;                                 \
        pfr[rt] = *(const f16x8*)&lp[prow * 64 +                          \
                    (((ks * 4 + lg) ^ (prow & 7)) << 3)];                 \
      }                                                                   \
      _Pragma("unroll") for (int ct = 0; ct < 4; ++ct) {                  \
        int vrow = ct * 16 + lr;                                          \
        f16x8 vfr = *(const f16x8*)&lv[cur][vrow * 64 +                   \
                    (((ks * 4 + lg) ^ (vrow & 7)) << 3)];                 \
        _Pragma("unroll") for (int rt = 0; rt < 2; ++rt)                  \
          acc_o[rt][ct] = mfma_h(pfr[rt], vfr, acc_o[rt][ct]);            \
      }                                                                   \
    }                                                                     \
  }

  LOADK(0, k0)
  STAGE(0, 0)

  for (int j = 0; j < SEQ / 64; j += 2) {
    ATTN_ITER(j, k0, k1)
    ATTN_ITER(j + 1, k1, k0)
  }

  // reduce l across the 16 lanes holding cols of each q-row
#pragma unroll
  for (int rt = 0; rt < 2; ++rt)
#pragma unroll
    for (int r = 0; r < 4; ++r) {
      float l = l_i[rt][r];
      l += __shfl_xor(l, 1, 16);
      l += __shfl_xor(l, 2, 16);
      l += __shfl_xor(l, 4, 16);
      l += __shfl_xor(l, 8, 16);
      l_i[rt][r] = l;
    }

  // epilogue: O/l * (S/sqrt(S-1)) * S^-0.5, fp16 to [b,s,(h d)]
  const int b = bh >> 4, hh = bh & 15;
  const float fact = 1.00024426f;
#pragma unroll
  for (int rt = 0; rt < 2; ++rt)
#pragma unroll
    for (int r = 0; r < 4; ++r) {
      float inv = fact / l_i[rt][r];
      int s = qt * 128 + w * 32 + rt * 16 + lg * 4 + r;
#pragma unroll
      for (int ct = 0; ct < 4; ++ct) {
        int d = ct * 16 + lr;
        float val = acc_o[rt][ct][r] * inv;
        o16[((size_t)(b * SEQ + s)) * HID + hh * DH + d] = f2h(val);
      }
    }
}

// ---------- launch ----------
extern "C" void kernel_launch(void* const* d_in, const int* in_sizes, int n_in,
                              void* d_out, int out_size, void* d_ws, size_t ws_size,
                              hipStream_t stream) {
  const float* x = (const float*)d_in[0];
  const float* w_qkv = (const float*)d_in[1];
  const float* w_o = (const float*)d_in[2];
  u16* ws = (u16*)d_ws;
  const size_t XS = (size_t)4096 * 1024;
  const size_t WQ = (size_t)3072 * 1024;
  const size_t WO = (size_t)1024 * 1024;
  u16* x16  = ws;           u16* wq16 = x16 + XS;
  u16* wo16 = wq16 + WQ;
  u16* q_f  = wo16 + WO;    u16* k_f  = q_f + XS;
  u16* vt_f = k_f + XS;     u16* o16  = vt_f + XS;

  prep_kernel<<<(NX4 + NQ4 + NO4) / 256, 256, 0, stream>>>(
      x, w_qkv, w_o, x16, wq16, wo16);
  gemm_qkv<<<dim3(32, 24), 256, 0, stream>>>(x16, wq16, q_f, k_f, vt_f);
  attn_kernel<<<dim3(32, 16), 256, 0, stream>>>(q_f, k_f, vt_f, o16);
  gemm_proj<<<dim3(32, 16), 256, 0, stream>>>(o16, wo16, (float*)d_out);
}

// Round 15
// 176.837 us; speedup vs baseline: 1.1945x; 1.1945x over previous
//
#include <hip/hip_runtime.h>

typedef unsigned short u16;
typedef _Float16 f16x8 __attribute__((ext_vector_type(8)));
typedef _Float16 f16x4 __attribute__((ext_vector_type(4)));
typedef float f32x4 __attribute__((ext_vector_type(4)));
typedef unsigned short u16x4 __attribute__((ext_vector_type(4)));

#define HID 1024
#define SEQ 2048
#define NH 16
#define DH 64

// ---------- helpers ----------
__device__ __forceinline__ u16 f2h(float f) {
  return __builtin_bit_cast(u16, (_Float16)f);
}
__device__ __forceinline__ f32x4 mfma_h(f16x8 a, f16x8 b, f32x4 c) {
  return __builtin_amdgcn_mfma_f32_16x16x32_f16(a, b, c, 0, 0, 0);
}
__device__ __forceinline__ f32x4 mfma_h16(f16x4 a, f16x4 b, f32x4 c) {
  return __builtin_amdgcn_mfma_f32_16x16x16f16(a, b, c, 0, 0, 0);
}
// raw v_exp_f32 (2^x); libm exp2f is the branchy OCML path (r8 regression).
__device__ __forceinline__ float fexp2(float x) {
#if __has_builtin(__builtin_amdgcn_exp2f)
  return __builtin_amdgcn_exp2f(x);
#else
  return __expf(0.69314718f * x);
#endif
}
// async global->LDS, 16B per lane; LDS dest is wave-uniform base + lane*16
__device__ __forceinline__ void g2l16(const u16* g, u16* l) {
  __builtin_amdgcn_global_load_lds(
      (const __attribute__((address_space(1))) unsigned int*)g,
      (__attribute__((address_space(3))) unsigned int*)l, 16, 0, 0);
}

// ---------- fused prep: x->fp16, w_qkv->fp16, w_o->fp16 ----------
#define NX4 ((4096 * 1024) / 4)
#define NQ4 ((3072 * 1024) / 4)
#define NO4 ((1024 * 1024) / 4)
__global__ __launch_bounds__(256) void prep_kernel(
    const float* __restrict__ x, const float* __restrict__ wq,
    const float* __restrict__ wo,
    u16* __restrict__ x16, u16* __restrict__ wq16, u16* __restrict__ wo16) {
  int i = blockIdx.x * 256 + threadIdx.x;
  const float4 v = (i < NX4) ? ((const float4*)x)[i]
                 : (i < NX4 + NQ4) ? ((const float4*)wq)[i - NX4]
                 : ((const float4*)wo)[i - NX4 - NQ4];
  u16* dst = (i < NX4) ? &x16[(size_t)i * 4]
           : (i < NX4 + NQ4) ? &wq16[(size_t)(i - NX4) * 4]
           : &wo16[(size_t)(i - NX4 - NQ4) * 4];
  u16x4 o;
  o[0] = f2h(v.x); o[1] = f2h(v.y); o[2] = f2h(v.z); o[3] = f2h(v.w);
  *(u16x4*)dst = o;
}

// ---------- QKV GEMM, fp16 single-term, BK=32 (r7-proven m97 layout) ----------
// C = (1/32) * A[4096x1024] * B[3072x1024]^T; epilogue scatters
// q (prescaled by d^-0.5 * log2e), k [b,h,s,d], vT [b,h,d,s'] where s' is the
// per-64-tile kv permutation matching attn's transpose-mfma A-frag order:
// kv' = (ct>>1)*32 + lgv*8 + (ct&1)*4 + rv  for kv = ct*16 + lgv*4 + rv.
__global__ __launch_bounds__(256, 3) void gemm_qkv(
    const u16* __restrict__ a16, const u16* __restrict__ b16,
    u16* __restrict__ qf, u16* __restrict__ kf, u16* __restrict__ vtf) {
  __shared__ __align__(16) u16 la[128 * 32], lb[128 * 32];
  const int t = threadIdx.x;
  const int lane = t & 63, w = t >> 6;
  const int wr = w >> 1, wc = w & 1;
  const int lr = lane & 15, lg = lane >> 4;
  const int br = blockIdx.x, bc = blockIdx.y;
  const f32x4 fzero = {0.f, 0.f, 0.f, 0.f};
  f32x4 acc[4][4];
#pragma unroll
  for (int i = 0; i < 4; ++i)
#pragma unroll
    for (int j = 0; j < 4; ++j) acc[i][j] = fzero;
  const int srow = t >> 2, scol = (t & 3) << 3;
  const u16* ga = a16 + (size_t)(br * 128 + srow) * HID + scol;
  const u16* gb = b16 + (size_t)(bc * 128 + srow) * HID + scol;
  const int lo16 = t * 8;
  for (int kk = 0; kk < HID; kk += 32) {
    g2l16(ga + kk, &la[lo16]);
    g2l16(ga + kk + (size_t)64 * HID, &la[lo16 + 2048]);
    g2l16(gb + kk, &lb[lo16]);
    g2l16(gb + kk + (size_t)64 * HID, &lb[lo16 + 2048]);
    __syncthreads();
    f16x8 ah[4], bh[4];
#pragma unroll
    for (int i = 0; i < 4; ++i)
      ah[i] = *(const f16x8*)&la[(wr * 64 + i * 16 + lr) * 32 + lg * 8];
#pragma unroll
    for (int j = 0; j < 4; ++j)
      bh[j] = *(const f16x8*)&lb[(wc * 64 + j * 16 + lr) * 32 + lg * 8];
#pragma unroll
    for (int i = 0; i < 4; ++i)
#pragma unroll
      for (int j = 0; j < 4; ++j) acc[i][j] = mfma_h(ah[i], bh[j], acc[i][j]);
    __syncthreads();
  }
  const int m0 = br * 128 + wr * 64, n0 = bc * 128 + wc * 64;
#pragma unroll
  for (int i = 0; i < 4; ++i)
#pragma unroll
    for (int j = 0; j < 4; ++j)
#pragma unroll
      for (int r = 0; r < 4; ++r) {
        int row = m0 + i * 16 + lg * 4 + r;       // C/D: row=(lane>>4)*4+reg
        int col = n0 + j * 16 + lr;               //      col=lane&15
        float val = acc[i][j][r] * 0.03125f;      // * HID^-0.5
        int b = row >> 11, s = row & 2047;
        int z = col >> 10, hh = (col >> 6) & 15, d = col & 63;
        int bhid = b * NH + hh;
        if (z == 0) {
          // * DH^-0.5 * log2(e): softmax uses raw v_exp_f32 (2^x)
          qf[((size_t)bhid * SEQ + s) * DH + d] = f2h(val * 0.18033688f);
        } else if (z == 1) {
          kf[((size_t)bhid * SEQ + s) * DH + d] = f2h(val);
        } else {
          // kv' permutation (see header comment)
          int kv = s & 63;
          int ct = kv >> 4, lgv = (kv >> 2) & 3, rv = kv & 3;
          int kvp = ((ct >> 1) << 5) | (lgv << 3) | ((ct & 1) << 2) | rv;
          int s2 = (s & ~63) | kvp;
          vtf[((size_t)bhid * DH + d) * SEQ + s2] = f2h(val);
        }
      }
}

// ---------- out-proj: single-term fp16, BK=32, 128x64 tile ----------
__global__ __launch_bounds__(256, 2) void gemm_proj(
    const u16* __restrict__ a16, const u16* __restrict__ b16,
    float* __restrict__ out) {
  __shared__ __align__(16) u16 la[128 * 32];
  __shared__ __align__(16) u16 lb[64 * 32];
  const int t = threadIdx.x;
  const int lane = t & 63, w = t >> 6;
  const int wr = w >> 1, wc = w & 1;
  const int lr = lane & 15, lg = lane >> 4;
  const int br = blockIdx.x, bc = blockIdx.y;
  const f32x4 fzero = {0.f, 0.f, 0.f, 0.f};
  f32x4 acc[4][2];
#pragma unroll
  for (int i = 0; i < 4; ++i)
#pragma unroll
    for (int j = 0; j < 2; ++j) acc[i][j] = fzero;
  const int srow = t >> 2, scol = (t & 3) << 3;
  const u16* ga = a16 + (size_t)(br * 128 + srow) * HID + scol;
  const u16* gb = b16 + (size_t)(bc * 64 + srow) * HID + scol;
  const int lo16 = t * 8;
  for (int kk = 0; kk < HID; kk += 32) {
    g2l16(ga + kk, &la[lo16]);
    g2l16(ga + kk + (size_t)64 * HID, &la[lo16 + 2048]);
    g2l16(gb + kk, &lb[lo16]);
    __syncthreads();
    f16x8 ah[4], bh[2];
#pragma unroll
    for (int i = 0; i < 4; ++i)
      ah[i] = *(const f16x8*)&la[(wr * 64 + i * 16 + lr) * 32 + lg * 8];
#pragma unroll
    for (int j = 0; j < 2; ++j)
      bh[j] = *(const f16x8*)&lb[(wc * 32 + j * 16 + lr) * 32 + lg * 8];
#pragma unroll
    for (int i = 0; i < 4; ++i)
#pragma unroll
      for (int j = 0; j < 2; ++j)
        acc[i][j] = mfma_h(ah[i], bh[j], acc[i][j]);
    __syncthreads();
  }
  const int m0 = br * 128 + wr * 64, n0 = bc * 64 + wc * 32;
#pragma unroll
  for (int i = 0; i < 4; ++i)
#pragma unroll
    for (int j = 0; j < 2; ++j)
#pragma unroll
      for (int r = 0; r < 4; ++r) {
        int row = m0 + i * 16 + lg * 4 + r;
        int col = n0 + j * 16 + lr;
        out[(size_t)row * HID + col] = acc[i][j][r] * 0.03125f;
      }
}

// ---------- flash attention: r13 skeleton + in-register P transpose ----------
// r15: the P LDS round-trip (lp, 8 ds_write_b64 + 4 ds_read_b128 + 1 barrier
// per iter) is replaced by a transpose-MFMA: feeding a C-layout P16 tile as
// the A-operand of mfma_f32_16x16x16_f16 with B=identity yields D = P16^T,
// which lands lane-> P[q'=lr][kv'=lg*4+r] -- A-operand-shaped after f16
// packing, under the kv' order baked into V's global store (mfma is k-order
// invariant). P handoff is wave-local, so no barrier needed: ONE barrier/iter.
// Transpose-mfma is exact (one nonzero product per output). LDS 48->32KB.
// K stays in LDS (r14 global-K regressed: vmem latency+drain > LDS cost).
// block: 128 q-rows x one (b,h). 4 waves; grid (bh=32, qt=16) = 512 blocks.
__global__ __launch_bounds__(256, 2) void attn_kernel(
    const u16* __restrict__ qf, const u16* __restrict__ kf,
    const u16* __restrict__ vtf, u16* __restrict__ o16) {
  __shared__ __align__(16) u16 lk[2][64 * 64];   // K tile [kv][d], fp16
  __shared__ __align__(16) u16 lv[2][64 * 64];   // V^T tile [d][kv'], fp16
  const int t = threadIdx.x;
  const int lane = t & 63, w = t >> 6;
  const int lr = lane & 15, lg = lane >> 4;
  const int bh = blockIdx.x, qt = blockIdx.y;
  const size_t base_qk = (size_t)bh * SEQ * DH;
  const size_t base_vt = (size_t)bh * DH * SEQ;

  // Q fragments pinned in registers (prescaled at creation)
  f16x8 qfr[2][2];
#pragma unroll
  for (int rt = 0; rt < 2; ++rt)
#pragma unroll
    for (int ks = 0; ks < 2; ++ks)
      qfr[rt][ks] = *(const f16x8*)&qf[base_qk +
          (size_t)(qt * 128 + w * 32 + rt * 16 + lr) * DH + ks * 32 + lg * 8];

  // identity B-frag for the transpose-mfma: B[n=lr][k=lg*4+j] = (n==k)
  f16x4 bI;
#pragma unroll
  for (int j = 0; j < 4; ++j) bI[j] = (_Float16)((lr == lg * 4 + j) ? 1.0f : 0.0f);

  const f32x4 fzero = {0.f, 0.f, 0.f, 0.f};
  f32x4 acc_o[2][4];
  float l_i[2][4];
#pragma unroll
  for (int rt = 0; rt < 2; ++rt)
#pragma unroll
    for (int r = 0; r < 4; ++r) l_i[rt][r] = 0.f;
#pragma unroll
  for (int rt = 0; rt < 2; ++rt)
#pragma unroll
    for (int ct = 0; ct < 4; ++ct) acc_o[rt][ct] = fzero;

  // staging: thread t fills phys chunk t (16B); source col is XOR-permuted
  const int srow = t >> 3;                 // 0..31
  const int scol = ((t & 7) ^ (srow & 7)) << 3;
  const int lo16 = t * 8;

  const u16* gk0 = kf + base_qk + (size_t)srow * DH + scol;
  const u16* gv0 = vtf + base_vt + (size_t)srow * SEQ + scol;

#define STAGE(buf, j)                                             \
  {                                                               \
    const u16* gk = gk0 + (size_t)(j) * 64 * DH;                  \
    g2l16(gk, &lk[buf][lo16]);                                    \
    g2l16(gk + 32 * DH, &lk[buf][lo16 + 2048]);                   \
    const u16* gv = gv0 + (j) * 64;                               \
    g2l16(gv, &lv[buf][lo16]);                                    \
    g2l16(gv + (size_t)32 * SEQ, &lv[buf][lo16 + 2048]);          \
  }

  STAGE(0, 0)

  for (int j = 0; j < SEQ / 64; ++j) {
    const int cur = j & 1;
    __syncthreads();   // stage(j) visible; all waves done with buf cur^1

    // S = Q K^T : 32 q-rows x 64 kv per wave (S in log2 domain)
    f32x4 sa[2][4];
#pragma unroll
    for (int rt = 0; rt < 2; ++rt)
#pragma unroll
      for (int ct = 0; ct < 4; ++ct) sa[rt][ct] = fzero;
#pragma unroll
    for (int ks = 0; ks < 2; ++ks)
#pragma unroll
      for (int ct = 0; ct < 4; ++ct) {
        int row = ct * 16 + lr;
        f16x8 kfr = *(const f16x8*)&lk[cur][row * 64 + (((ks * 4 + lg) ^ (row & 7)) << 3)];
#pragma unroll
        for (int rt = 0; rt < 2; ++rt) sa[rt][ct] = mfma_h(qfr[rt][ks], kfr, sa[rt][ct]);
      }

    if (j + 1 < SEQ / 64) STAGE(cur ^ 1, j + 1)   // prefetch (other buffers)

    // softmax (fixed max=0) + in-register transpose to A-layout.
    // tr = mfma16(P16_C-layout_as_A, I) = P16^T in C/D layout:
    //   lane -> P[q'=lr][kv'local = lg*4 + r] per 16-tile ct.
    // A-frag pack order: pfr[rt][ks][j] = tile(ks*2+(j>>2)) value r=(j&3)
    //   -> kv = ct*16 + lg*4 + r, matching V's kv' global-store permute.
    f16x8 pfr[2][2];
#pragma unroll
    for (int rt = 0; rt < 2; ++rt) {
      f32x4 tr[4];
#pragma unroll
      for (int ct = 0; ct < 4; ++ct) {
        f16x4 a4;
#pragma unroll
        for (int r = 0; r < 4; ++r) {
          float p = fexp2(sa[rt][ct][r]);
          l_i[rt][r] += p;
          a4[r] = (_Float16)p;
        }
        tr[ct] = mfma_h16(a4, bI, fzero);
      }
#pragma unroll
      for (int ks = 0; ks < 2; ++ks) {
        f16x8 pf;
#pragma unroll
        for (int j2 = 0; j2 < 8; ++j2)
          pf[j2] = (_Float16)tr[ks * 2 + (j2 >> 2)][j2 & 3];
        pfr[rt][ks] = pf;
      }
    }

    // O += P V (k-order = kv' permute; A and B share it -> sum invariant)
#pragma unroll
    for (int ks = 0; ks < 2; ++ks)
#pragma unroll
      for (int ct = 0; ct < 4; ++ct) {
        int vrow = ct * 16 + lr;
        f16x8 vfr = *(const f16x8*)&lv[cur][vrow * 64 + (((ks * 4 + lg) ^ (vrow & 7)) << 3)];
#pragma unroll
        for (int rt = 0; rt < 2; ++rt) acc_o[rt][ct] = mfma_h(pfr[rt][ks], vfr, acc_o[rt][ct]);
      }
  }

  // reduce l across the 16 lanes holding cols of each q-row
#pragma unroll
  for (int rt = 0; rt < 2; ++rt)
#pragma unroll
    for (int r = 0; r < 4; ++r) {
      float l = l_i[rt][r];
      l += __shfl_xor(l, 1, 16);
      l += __shfl_xor(l, 2, 16);
      l += __shfl_xor(l, 4, 16);
      l += __shfl_xor(l, 8, 16);
      l_i[rt][r] = l;
    }

  // epilogue: O/l * (S/sqrt(S-1)) * S^-0.5, fp16 to [b,s,(h d)]
  const int b = bh >> 4, hh = bh & 15;
  const float fact = 1.00024426f;
#pragma unroll
  for (int rt = 0; rt < 2; ++rt)
#pragma unroll
    for (int r = 0; r < 4; ++r) {
      float inv = fact / l_i[rt][r];
      int s = qt * 128 + w * 32 + rt * 16 + lg * 4 + r;
#pragma unroll
      for (int ct = 0; ct < 4; ++ct) {
        int d = ct * 16 + lr;
        float val = acc_o[rt][ct][r] * inv;
        o16[((size_t)(b * SEQ + s)) * HID + hh * DH + d] = f2h(val);
      }
    }
}

// ---------- launch ----------
extern "C" void kernel_launch(void* const* d_in, const int* in_sizes, int n_in,
                              void* d_out, int out_size, void* d_ws, size_t ws_size,
                              hipStream_t stream) {
  const float* x = (const float*)d_in[0];
  const float* w_qkv = (const float*)d_in[1];
  const float* w_o = (const float*)d_in[2];
  u16* ws = (u16*)d_ws;
  const size_t XS = (size_t)4096 * 1024;
  const size_t WQ = (size_t)3072 * 1024;
  const size_t WO = (size_t)1024 * 1024;
  u16* x16  = ws;           u16* wq16 = x16 + XS;
  u16* wo16 = wq16 + WQ;
  u16* q_f  = wo16 + WO;    u16* k_f  = q_f + XS;
  u16* vt_f = k_f + XS;     u16* o16  = vt_f + XS;

  prep_kernel<<<(NX4 + NQ4 + NO4) / 256, 256, 0, stream>>>(
      x, w_qkv, w_o, x16, wq16, wo16);
  gemm_qkv<<<dim3(32, 24), 256, 0, stream>>>(x16, wq16, q_f, k_f, vt_f);
  attn_kernel<<<dim3(32, 16), 256, 0, stream>>>(q_f, k_f, vt_f, o16);
  gemm_proj<<<dim3(32, 16), 256, 0, stream>>>(o16, wo16, (float*)d_out);
}